// Round 6
// baseline (208.098 us; speedup 1.0000x reference)
//
#include <hip/hip_runtime.h>

// HyperLinear, single-launch fused (r5's 3 kernels -> 1 kernel + 2 SW grid barriers):
//  Phase A (setup):  Bb[576][256] bf16 (512 permuted fcwp_w rows + 64 c-rows),
//                    B2[256][352] bf16 (target_w | fcwe_w | fcbp_w | fcwe_b | bias | 0),
//                    A2[2048][352] bf16 (x | <t hole> | h | sx | 1 | 0).
//  Phase B (gemm1):  G[2048][576] bf16 = A2[:,0:256] @ Bb^T   (288 64x64 tiles)
//  Phase C (gemm2):  out = [x|t|h|sx|1] @ B2^T, t folded from G in prologue.
//  Grid barriers: per-block magic flags in d_ws (poisoned 0xAA each launch, so
//  flags always start != magic); release store + agent-scope spin + acquire fence.
//  288 blocks x 69 KB LDS -> 2 blocks/CU -> all co-resident (512 capacity).

#define B_TOT 2048
#define NP    8
#define CIN   256
#define COUT  256
#define MID   64
#define NB1   576
#define K2    352
#define LDG   576
#define LDAS  136
#define LDA2S 360
#define LDB2S 360
#define GRID  288
#define MAGIC1 0x13579BDFu
#define MAGIC2 0x2468ACE1u

typedef short  short8  __attribute__((ext_vector_type(8)));
typedef float  floatx4 __attribute__((ext_vector_type(4)));

__device__ __forceinline__ unsigned short f2bf(float f) {
    union { float f; unsigned u; } v; v.f = f;
    unsigned r = v.u + 0x7FFFu + ((v.u >> 16) & 1u);
    return (unsigned short)(r >> 16);
}
__device__ __forceinline__ float bf2f(unsigned short u) {
    union { unsigned u; float f; } v; v.u = ((unsigned)u) << 16;
    return v.f;
}

__device__ __forceinline__ void grid_barrier(unsigned* flags, unsigned magic) {
    __syncthreads();
    __threadfence();   // release: make this block's global writes device-visible
    if (threadIdx.x == 0)
        __hip_atomic_store(&flags[blockIdx.x], magic,
                           __ATOMIC_RELEASE, __HIP_MEMORY_SCOPE_AGENT);
    const int t = threadIdx.x;
    int ok;
    do {
        ok = (__hip_atomic_load(&flags[t], __ATOMIC_RELAXED,
                                __HIP_MEMORY_SCOPE_AGENT) == magic);
        if (t < GRID - 256)
            ok = ok && (__hip_atomic_load(&flags[256 + t], __ATOMIC_RELAXED,
                                          __HIP_MEMORY_SCOPE_AGENT) == magic);
    } while (!__syncthreads_and(ok));
    __threadfence();   // acquire: invalidate stale cached lines before reads
}

__global__ __launch_bounds__(256) void hyper_all(
    const float* __restrict__ x, const float* __restrict__ h,
    const float* __restrict__ index,
    const float* __restrict__ target_w, const float* __restrict__ target_b,
    const float* __restrict__ fcwp_w, const float* __restrict__ fcwp_b,
    const float* __restrict__ fcwi_w, const float* __restrict__ fcwi_b,
    const float* __restrict__ fcwe_w, const float* __restrict__ fcwe_b,
    const float* __restrict__ fcbp_w, const float* __restrict__ fcbp_b,
    const float* __restrict__ fcbi_w, const float* __restrict__ fcbi_b,
    unsigned short* __restrict__ Bb, unsigned short* __restrict__ B2,
    unsigned short* __restrict__ A2, unsigned short* __restrict__ G,
    unsigned* __restrict__ flagA, unsigned* __restrict__ flagB,
    float* __restrict__ out)
{
    __shared__ __align__(16) char smem[69120];   // max over phases (phase C)
    const int blk = blockIdx.x, tid = threadIdx.x;

    // ================= Phase A: setup (blocks 0..120) =================
    {
        unsigned short (*Lt)[68] = (unsigned short (*)[68])smem;          // 8704 B
        float (*red)[8] = (float (*)[8])(smem + 8704);                    // 1024 B

        if (blk < 32) {
            // Bb[n][i] = bf16(fcwp_w[i*512+n]); 64x64 tile transpose
            const int i0 = (blk >> 3) * 64, n0 = (blk & 7) * 64;
            const int r = tid >> 4, c4 = (tid & 15) * 4;
            #pragma unroll
            for (int k = 0; k < 4; ++k) {
                int ii = r + k * 16;
                float4 v = *(const float4*)(fcwp_w + (size_t)(i0 + ii) * 512 + n0 + c4);
                Lt[c4 + 0][ii] = f2bf(v.x); Lt[c4 + 1][ii] = f2bf(v.y);
                Lt[c4 + 2][ii] = f2bf(v.z); Lt[c4 + 3][ii] = f2bf(v.w);
            }
            __syncthreads();
            const int nn = tid >> 2, ic0 = (tid & 3) * 16;
            #pragma unroll
            for (int k = 0; k < 4; ++k) {
                int ic = ic0 + k * 4;
                ushort4 o4;
                o4.x = Lt[nn][ic]; o4.y = Lt[nn][ic + 1];
                o4.z = Lt[nn][ic + 2]; o4.w = Lt[nn][ic + 3];
                *(ushort4*)&Bb[(size_t)(n0 + nn) * CIN + i0 + ic] = o4;
            }
        } else if (blk < 36) {
            // c rows: Bb[512+m][i], e = i*64+m
            const int i0 = (blk - 32) * 64;
            const float x0 = index[0], x1 = index[1], x2 = index[2], x3 = index[3];
            const int r = tid >> 4, c4 = (tid & 15) * 4;
            #pragma unroll
            for (int k = 0; k < 4; ++k) {
                int ii = r + k * 16;
                int e = (i0 + ii) * 64 + c4;
                float4 pb = *(const float4*)(fcwp_b + e);
                float4 ib = *(const float4*)(fcwi_b + e);
                float pbv[4] = {pb.x, pb.y, pb.z, pb.w};
                float ibv[4] = {ib.x, ib.y, ib.z, ib.w};
                #pragma unroll
                for (int j = 0; j < 4; ++j) {
                    float4 wv = *(const float4*)(fcwi_w + (size_t)(e + j) * 4);
                    Lt[c4 + j][ii] = f2bf(pbv[j] + ibv[j]
                        + x0 * wv.x + x1 * wv.y + x2 * wv.z + x3 * wv.w);
                }
            }
            __syncthreads();
            const int mm = tid >> 2, ic0 = (tid & 3) * 16;
            #pragma unroll
            for (int k = 0; k < 4; ++k) {
                int ic = ic0 + k * 4;
                ushort4 o4;
                o4.x = Lt[mm][ic]; o4.y = Lt[mm][ic + 1];
                o4.z = Lt[mm][ic + 2]; o4.w = Lt[mm][ic + 3];
                *(ushort4*)&Bb[(size_t)(512 + mm) * CIN + i0 + ic] = o4;
            }
        } else if (blk < 52) {
            // B2 cols [0,256) = target_w
            int base = (blk - 36) * 4096;
            #pragma unroll
            for (int k = 0; k < 4; ++k) {
                int e = base + k * 1024 + tid * 4;
                int o = e >> 8, c = e & 255;
                float4 v = *(const float4*)(target_w + e);
                ushort4 o4;
                o4.x = f2bf(v.x); o4.y = f2bf(v.y); o4.z = f2bf(v.z); o4.w = f2bf(v.w);
                *(ushort4*)&B2[(size_t)o * K2 + c] = o4;
            }
        } else if (blk < 56) {
            // B2 cols [256,320) = fcwe_w
            int base = (blk - 52) * 4096;
            #pragma unroll
            for (int k = 0; k < 4; ++k) {
                int e = base + k * 1024 + tid * 4;
                int o = e >> 6, m = e & 63;
                float4 v = *(const float4*)(fcwe_w + e);
                ushort4 o4;
                o4.x = f2bf(v.x); o4.y = f2bf(v.y); o4.z = f2bf(v.z); o4.w = f2bf(v.w);
                *(ushort4*)&B2[(size_t)o * K2 + 256 + m] = o4;
            }
        } else if (blk == 56) {
            // B2 tail per output o
            int o = tid;
            size_t bo = (size_t)o * K2;
            float4 p0 = *(const float4*)(fcbp_w + (size_t)o * 8);
            float4 p1 = *(const float4*)(fcbp_w + (size_t)o * 8 + 4);
            B2[bo + 320] = f2bf(p0.x); B2[bo + 321] = f2bf(p0.y);
            B2[bo + 322] = f2bf(p0.z); B2[bo + 323] = f2bf(p0.w);
            B2[bo + 324] = f2bf(p1.x); B2[bo + 325] = f2bf(p1.y);
            B2[bo + 326] = f2bf(p1.z); B2[bo + 327] = f2bf(p1.w);
            B2[bo + 328] = f2bf(fcwe_b[o]);
            float bc = target_b[o] + fcbp_b[o] + fcbi_b[o]
                     + index[0] * fcbi_w[o * 4]     + index[1] * fcbi_w[o * 4 + 1]
                     + index[2] * fcbi_w[o * 4 + 2] + index[3] * fcbi_w[o * 4 + 3];
            B2[bo + 329] = f2bf(bc);
            #pragma unroll
            for (int z = 330; z < K2; ++z) B2[bo + z] = 0;
        } else if (blk < 121) {
            // A2 rows: x cols, h cols, sx, ones, zero pad
            const int r0 = (blk - 57) * 32;
            const int rr = tid >> 3, cpos = tid & 7;
            const int b = r0 + rr;
            const float* xrow = x + (size_t)b * CIN;
            float psum = 0.f;
            #pragma unroll
            for (int k = 0; k < 8; ++k) {
                int c = (cpos + k * 8) * 4;
                float4 v = *(const float4*)(xrow + c);
                psum += v.x + v.y + v.z + v.w;
                ushort4 o4;
                o4.x = f2bf(v.x); o4.y = f2bf(v.y); o4.z = f2bf(v.z); o4.w = f2bf(v.w);
                *(ushort4*)&A2[(size_t)b * K2 + c] = o4;
            }
            red[rr][cpos] = psum;
            A2[(size_t)b * K2 + 320 + cpos] = f2bf(h[(size_t)r0 * NP + tid]);
            for (int idx = tid; idx < 32 * 22; idx += 256) {
                int r2 = idx / 22, c2 = 330 + idx % 22;
                A2[(size_t)(r0 + r2) * K2 + c2] = 0;
            }
            __syncthreads();
            if (tid < 32) {
                float s = red[tid][0] + red[tid][1] + red[tid][2] + red[tid][3]
                        + red[tid][4] + red[tid][5] + red[tid][6] + red[tid][7];
                size_t base = (size_t)(r0 + tid) * K2;
                A2[base + 328] = f2bf(s);
                A2[base + 329] = 0x3F80;   // 1.0 bf16
            }
        }
    }

    grid_barrier(flagA, MAGIC1);

    // ================= Phase B: gemm1 G = x_bf @ Bb^T (288 units) =========
    {
        unsigned short* As = (unsigned short*)smem;              // 64*136*2 = 17408
        unsigned short* Bs = (unsigned short*)(smem + 17408);    // 17408
        const int lane = tid & 63, w = tid >> 6;
        const int col = lane & 15, quad = lane >> 4;
        const int mb = (blk & 31) * 64, nb = (blk >> 5) * 64;

        floatx4 acc[4] = {floatx4{0,0,0,0}, floatx4{0,0,0,0},
                          floatx4{0,0,0,0}, floatx4{0,0,0,0}};

        for (int kh = 0; kh < 2; ++kh) {
            const int k0 = kh * 128;
            __syncthreads();
            #pragma unroll
            for (int it = 0; it < 4; ++it) {
                int idx = it * 256 + tid;
                int r = idx >> 4, c = (idx & 15) * 8;
                *(uint4*)&As[r * LDAS + c] =
                    *(const uint4*)(A2 + (size_t)(mb + r) * K2 + k0 + c);
                *(uint4*)&Bs[r * LDAS + c] =
                    *(const uint4*)(Bb + (size_t)(nb + r) * CIN + k0 + c);
            }
            __syncthreads();
            #pragma unroll
            for (int ks = 0; ks < 4; ++ks) {
                int kc = ks * 32 + quad * 8;
                short8 af = *(const short8*)&As[(w * 16 + col) * LDAS + kc];
                #pragma unroll
                for (int f = 0; f < 4; ++f) {
                    short8 bfr = *(const short8*)&Bs[(f * 16 + col) * LDAS + kc];
                    acc[f] = __builtin_amdgcn_mfma_f32_16x16x32_bf16(af, bfr, acc[f], 0, 0, 0);
                }
            }
        }
        #pragma unroll
        for (int f = 0; f < 4; ++f)
            #pragma unroll
            for (int r = 0; r < 4; ++r)
                G[(size_t)(mb + w * 16 + quad * 4 + r) * LDG + nb + f * 16 + col]
                    = f2bf(acc[f][r]);
    }

    grid_barrier(flagB, MAGIC2);

    // ================= Phase C: gemm2 out = [x|t|h|sx|1] @ B2^T ===========
    if (blk < 256) {
        unsigned short* As = (unsigned short*)smem;              // 32*360*2 = 23040
        unsigned short* Bs = (unsigned short*)(smem + 23040);    // 64*360*2 = 46080
        const int lane = tid & 63, w = tid >> 6;
        const int col = lane & 15, quad = lane >> 4;
        const int b0 = (blk & 63) * 32, n0 = (blk >> 6) * 64;

        #pragma unroll
        for (int it = 0; it < 4; ++it) {
            int idx = it * 256 + tid;
            int r = idx >> 5, c = (idx & 31) * 8;
            *(uint4*)&As[r * LDA2S + c] =
                *(const uint4*)(A2 + (size_t)(b0 + r) * K2 + c);
        }
        if (tid < 128) {
            int r = tid >> 2, c = 320 + (tid & 3) * 8;
            *(uint4*)&As[r * LDA2S + c] =
                *(const uint4*)(A2 + (size_t)(b0 + r) * K2 + c);
        }
        #pragma unroll
        for (int it = 0; it < 11; ++it) {
            int idx = it * 256 + tid;
            int r = idx / 44, c = (idx % 44) * 8;
            *(uint4*)&Bs[r * LDB2S + c] =
                *(const uint4*)(B2 + (size_t)(n0 + r) * K2 + c);
        }
        {   // fold t[s][m] into As cols [256,320)
            int s = tid >> 3, mg = tid & 7;
            const unsigned short* grow = G + (size_t)(b0 + s) * LDG;
            ushort4 hu0 = *(const ushort4*)(A2 + (size_t)(b0 + s) * K2 + 320);
            ushort4 hu1 = *(const ushort4*)(A2 + (size_t)(b0 + s) * K2 + 324);
            float hv[8] = {bf2f(hu0.x), bf2f(hu0.y), bf2f(hu0.z), bf2f(hu0.w),
                           bf2f(hu1.x), bf2f(hu1.y), bf2f(hu1.z), bf2f(hu1.w)};
            ushort4 cu0 = *(const ushort4*)(grow + 512 + mg * 8);
            ushort4 cu1 = *(const ushort4*)(grow + 512 + mg * 8 + 4);
            float t[8] = {bf2f(cu0.x), bf2f(cu0.y), bf2f(cu0.z), bf2f(cu0.w),
                          bf2f(cu1.x), bf2f(cu1.y), bf2f(cu1.z), bf2f(cu1.w)};
            #pragma unroll
            for (int j = 0; j < 8; ++j) {
                const unsigned short* gp = grow + (mg * 8 + j) * 8;
                ushort4 g0 = *(const ushort4*)gp;
                ushort4 g1 = *(const ushort4*)(gp + 4);
                t[j] += hv[0] * bf2f(g0.x) + hv[1] * bf2f(g0.y)
                      + hv[2] * bf2f(g0.z) + hv[3] * bf2f(g0.w)
                      + hv[4] * bf2f(g1.x) + hv[5] * bf2f(g1.y)
                      + hv[6] * bf2f(g1.z) + hv[7] * bf2f(g1.w);
            }
            ushort4 t0, t1;
            t0.x = f2bf(t[0]); t0.y = f2bf(t[1]); t0.z = f2bf(t[2]); t0.w = f2bf(t[3]);
            t1.x = f2bf(t[4]); t1.y = f2bf(t[5]); t1.z = f2bf(t[6]); t1.w = f2bf(t[7]);
            *(ushort4*)&As[s * LDA2S + 256 + mg * 8]     = t0;
            *(ushort4*)&As[s * LDA2S + 256 + mg * 8 + 4] = t1;
        }
        __syncthreads();

        const int mr = (w & 1) * 16, nbw = (w >> 1) * 32;
        floatx4 acc[2] = {floatx4{0,0,0,0}, floatx4{0,0,0,0}};
        #pragma unroll
        for (int ks = 0; ks < 11; ++ks) {
            int kc = ks * 32 + quad * 8;
            short8 af = *(const short8*)&As[(mr + col) * LDA2S + kc];
            #pragma unroll
            for (int f = 0; f < 2; ++f) {
                short8 bfr = *(const short8*)&Bs[(nbw + f * 16 + col) * LDB2S + kc];
                acc[f] = __builtin_amdgcn_mfma_f32_16x16x32_bf16(af, bfr, acc[f], 0, 0, 0);
            }
        }
        #pragma unroll
        for (int f = 0; f < 2; ++f)
            #pragma unroll
            for (int r = 0; r < 4; ++r)
                out[(size_t)(b0 + mr + quad * 4 + r) * COUT + n0 + nbw + f * 16 + col]
                    = acc[f][r];
    }
}

extern "C" void kernel_launch(void* const* d_in, const int* in_sizes, int n_in,
                              void* d_out, int out_size, void* d_ws, size_t ws_size,
                              hipStream_t stream) {
    const float* x        = (const float*)d_in[0];
    const float* h        = (const float*)d_in[1];
    const float* index    = (const float*)d_in[2];
    const float* target_w = (const float*)d_in[3];
    const float* target_b = (const float*)d_in[4];
    const float* fcwp_w   = (const float*)d_in[5];
    const float* fcwp_b   = (const float*)d_in[6];
    const float* fcwi_w   = (const float*)d_in[7];
    const float* fcwi_b   = (const float*)d_in[8];
    const float* fcwe_w   = (const float*)d_in[9];
    const float* fcwe_b   = (const float*)d_in[10];
    const float* fcbp_w   = (const float*)d_in[11];
    const float* fcbp_b   = (const float*)d_in[12];
    const float* fcbi_w   = (const float*)d_in[13];
    const float* fcbi_b   = (const float*)d_in[14];
    float* out = (float*)d_out;

    char* ws = (char*)d_ws;
    unsigned short* Bb = (unsigned short*)ws;               // 576*256*2  = 294912
    unsigned short* B2 = (unsigned short*)(ws + 294912);    // 256*352*2  = 180224
    unsigned short* A2 = (unsigned short*)(ws + 475136);    // 2048*352*2 = 1441792
    unsigned short* G  = (unsigned short*)(ws + 1916928);   // 2048*576*2 = 2359296
    unsigned* flagA    = (unsigned*)(ws + 4276224);         // 288*4 = 1152
    unsigned* flagB    = (unsigned*)(ws + 4277376);         // 288*4 = 1152

    hyper_all<<<GRID, 256, 0, stream>>>(
        x, h, index, target_w, target_b, fcwp_w, fcwp_b, fcwi_w, fcwi_b,
        fcwe_w, fcwe_b, fcbp_w, fcbp_b, fcbi_w, fcbi_b,
        Bb, B2, A2, G, flagA, flagB, out);
}

// Round 7
// 93.352 us; speedup vs baseline: 2.2292x; 2.2292x over previous
//
#include <hip/hip_runtime.h>

// HyperLinear, lean 3-kernel split (A2 intermediate eliminated):
//  setup_bb:  Bb[576][256] bf16 (512 permuted fcwp_w rows + 64 c-rows). 36 blocks.
//  gemm1:     blocks 0..287: G[2048][576] bf16 = bf16(x) @ Bb^T (64x64 tiles,
//             x converted fp32->bf16 during LDS staging).
//             blocks 288..308: build B2[256][352] bf16
//             (target_w | fcwe_w | fcbp_w | fcwe_b | bias_const | 0).
//  gemm2:     out[2048][256] f32 = [x | t | h | sx | 1 | 0] @ B2^T, with the
//             A-panel built entirely in LDS: x converted in staging, t folded
//             from G (t[s][m] = sum_p h[s][p]*G[s][m*8+p] + G[s][512+m]),
//             sx = row-sum of x, h read fp32.

#define B_TOT 2048
#define NP    8
#define CIN   256
#define COUT  256
#define MID   64
#define K2    352
#define LDG   576
#define LDAS  136
#define LDA2S 360
#define LDB2S 360

typedef short  short8  __attribute__((ext_vector_type(8)));
typedef float  floatx4 __attribute__((ext_vector_type(4)));

__device__ __forceinline__ unsigned short f2bf(float f) {
    union { float f; unsigned u; } v; v.f = f;
    unsigned r = v.u + 0x7FFFu + ((v.u >> 16) & 1u);
    return (unsigned short)(r >> 16);
}
__device__ __forceinline__ float bf2f(unsigned short u) {
    union { unsigned u; float f; } v; v.u = ((unsigned)u) << 16;
    return v.f;
}

// ---------------- setup: Bb only (36 blocks) ----------------
__global__ __launch_bounds__(256) void setup_bb(
    const float* __restrict__ index,
    const float* __restrict__ fcwp_w, const float* __restrict__ fcwp_b,
    const float* __restrict__ fcwi_w, const float* __restrict__ fcwi_b,
    unsigned short* __restrict__ Bb)
{
    __shared__ unsigned short Lt[64][68];
    const int blk = blockIdx.x, tid = threadIdx.x;

    if (blk < 32) {
        // Bb[n][i] = bf16(fcwp_w[i*512+n]); 64x64 tile transpose
        const int i0 = (blk >> 3) * 64, n0 = (blk & 7) * 64;
        const int r = tid >> 4, c4 = (tid & 15) * 4;
        #pragma unroll
        for (int k = 0; k < 4; ++k) {
            int ii = r + k * 16;
            float4 v = *(const float4*)(fcwp_w + (size_t)(i0 + ii) * 512 + n0 + c4);
            Lt[c4 + 0][ii] = f2bf(v.x); Lt[c4 + 1][ii] = f2bf(v.y);
            Lt[c4 + 2][ii] = f2bf(v.z); Lt[c4 + 3][ii] = f2bf(v.w);
        }
        __syncthreads();
        const int nn = tid >> 2, ic0 = (tid & 3) * 16;
        #pragma unroll
        for (int k = 0; k < 4; ++k) {
            int ic = ic0 + k * 4;
            ushort4 o4;
            o4.x = Lt[nn][ic]; o4.y = Lt[nn][ic + 1];
            o4.z = Lt[nn][ic + 2]; o4.w = Lt[nn][ic + 3];
            *(ushort4*)&Bb[(size_t)(n0 + nn) * CIN + i0 + ic] = o4;
        }
    } else {
        // c rows: Bb[512+m][i], e = i*64+m
        const int i0 = (blk - 32) * 64;
        const float x0 = index[0], x1 = index[1], x2 = index[2], x3 = index[3];
        const int r = tid >> 4, c4 = (tid & 15) * 4;
        #pragma unroll
        for (int k = 0; k < 4; ++k) {
            int ii = r + k * 16;
            int e = (i0 + ii) * 64 + c4;
            float4 pb = *(const float4*)(fcwp_b + e);
            float4 ib = *(const float4*)(fcwi_b + e);
            float pbv[4] = {pb.x, pb.y, pb.z, pb.w};
            float ibv[4] = {ib.x, ib.y, ib.z, ib.w};
            #pragma unroll
            for (int j = 0; j < 4; ++j) {
                float4 wv = *(const float4*)(fcwi_w + (size_t)(e + j) * 4);
                Lt[c4 + j][ii] = f2bf(pbv[j] + ibv[j]
                    + x0 * wv.x + x1 * wv.y + x2 * wv.z + x3 * wv.w);
            }
        }
        __syncthreads();
        const int mm = tid >> 2, ic0 = (tid & 3) * 16;
        #pragma unroll
        for (int k = 0; k < 4; ++k) {
            int ic = ic0 + k * 4;
            ushort4 o4;
            o4.x = Lt[mm][ic]; o4.y = Lt[mm][ic + 1];
            o4.z = Lt[mm][ic + 2]; o4.w = Lt[mm][ic + 3];
            *(ushort4*)&Bb[(size_t)(512 + mm) * CIN + i0 + ic] = o4;
        }
    }
}

// ------- gemm1 (blocks 0..287) + B2 build (blocks 288..308) -------
__global__ __launch_bounds__(256) void gemm1_kernel(
    const float* __restrict__ x,             // [2048][256]
    const unsigned short* __restrict__ Bb,   // [576][256]
    const float* __restrict__ index,
    const float* __restrict__ target_w, const float* __restrict__ target_b,
    const float* __restrict__ fcwe_w, const float* __restrict__ fcwe_b,
    const float* __restrict__ fcbp_w, const float* __restrict__ fcbp_b,
    const float* __restrict__ fcbi_w, const float* __restrict__ fcbi_b,
    unsigned short* __restrict__ B2,         // [256][352]
    unsigned short* __restrict__ G)          // [2048][576] bf16
{
    __shared__ unsigned short As[64 * LDAS];
    __shared__ unsigned short Bs[64 * LDAS];
    const int blk = blockIdx.x, tid = threadIdx.x;

    if (blk < 288) {
        const int lane = tid & 63, w = tid >> 6;
        const int col = lane & 15, quad = lane >> 4;
        const int mb = (blk & 31) * 64, nb = (blk >> 5) * 64;

        floatx4 acc[4] = {floatx4{0,0,0,0}, floatx4{0,0,0,0},
                          floatx4{0,0,0,0}, floatx4{0,0,0,0}};

        for (int kh = 0; kh < 2; ++kh) {
            const int k0 = kh * 128;
            __syncthreads();
            // stage As: x fp32 -> bf16, 64 rows x 128 cols
            #pragma unroll
            for (int it = 0; it < 8; ++it) {
                int idx = it * 256 + tid;
                int r = idx >> 5, c = (idx & 31) * 4;
                float4 v = *(const float4*)(x + (size_t)(mb + r) * CIN + k0 + c);
                ushort4 o4;
                o4.x = f2bf(v.x); o4.y = f2bf(v.y); o4.z = f2bf(v.z); o4.w = f2bf(v.w);
                *(ushort4*)&As[r * LDAS + c] = o4;
            }
            // stage Bs from Bb (bf16 copy)
            #pragma unroll
            for (int it = 0; it < 4; ++it) {
                int idx = it * 256 + tid;
                int r = idx >> 4, c = (idx & 15) * 8;
                *(uint4*)&Bs[r * LDAS + c] =
                    *(const uint4*)(Bb + (size_t)(nb + r) * CIN + k0 + c);
            }
            __syncthreads();
            #pragma unroll
            for (int ks = 0; ks < 4; ++ks) {
                int kc = ks * 32 + quad * 8;
                short8 af = *(const short8*)&As[(w * 16 + col) * LDAS + kc];
                #pragma unroll
                for (int f = 0; f < 4; ++f) {
                    short8 bfr = *(const short8*)&Bs[(f * 16 + col) * LDAS + kc];
                    acc[f] = __builtin_amdgcn_mfma_f32_16x16x32_bf16(af, bfr, acc[f], 0, 0, 0);
                }
            }
        }
        #pragma unroll
        for (int f = 0; f < 4; ++f)
            #pragma unroll
            for (int r = 0; r < 4; ++r)
                G[(size_t)(mb + w * 16 + quad * 4 + r) * LDG + nb + f * 16 + col]
                    = f2bf(acc[f][r]);
    } else if (blk < 304) {
        // B2 cols [0,256) = target_w
        int base = (blk - 288) * 4096;
        #pragma unroll
        for (int k = 0; k < 4; ++k) {
            int e = base + k * 1024 + tid * 4;
            int o = e >> 8, c = e & 255;
            float4 v = *(const float4*)(target_w + e);
            ushort4 o4;
            o4.x = f2bf(v.x); o4.y = f2bf(v.y); o4.z = f2bf(v.z); o4.w = f2bf(v.w);
            *(ushort4*)&B2[(size_t)o * K2 + c] = o4;
        }
    } else if (blk < 308) {
        // B2 cols [256,320) = fcwe_w
        int base = (blk - 304) * 4096;
        #pragma unroll
        for (int k = 0; k < 4; ++k) {
            int e = base + k * 1024 + tid * 4;
            int o = e >> 6, m = e & 63;
            float4 v = *(const float4*)(fcwe_w + e);
            ushort4 o4;
            o4.x = f2bf(v.x); o4.y = f2bf(v.y); o4.z = f2bf(v.z); o4.w = f2bf(v.w);
            *(ushort4*)&B2[(size_t)o * K2 + 256 + m] = o4;
        }
    } else {
        // B2 tail per output o
        int o = tid;
        size_t bo = (size_t)o * K2;
        float4 p0 = *(const float4*)(fcbp_w + (size_t)o * 8);
        float4 p1 = *(const float4*)(fcbp_w + (size_t)o * 8 + 4);
        B2[bo + 320] = f2bf(p0.x); B2[bo + 321] = f2bf(p0.y);
        B2[bo + 322] = f2bf(p0.z); B2[bo + 323] = f2bf(p0.w);
        B2[bo + 324] = f2bf(p1.x); B2[bo + 325] = f2bf(p1.y);
        B2[bo + 326] = f2bf(p1.z); B2[bo + 327] = f2bf(p1.w);
        B2[bo + 328] = f2bf(fcwe_b[o]);
        float bc = target_b[o] + fcbp_b[o] + fcbi_b[o]
                 + index[0] * fcbi_w[o * 4]     + index[1] * fcbi_w[o * 4 + 1]
                 + index[2] * fcbi_w[o * 4 + 2] + index[3] * fcbi_w[o * 4 + 3];
        B2[bo + 329] = f2bf(bc);
        #pragma unroll
        for (int z = 330; z < K2; ++z) B2[bo + z] = 0;
    }
}

// ------- gemm2: out = [x|t|h|sx|1|0] @ B2^T, A-panel built in LDS -------
__global__ __launch_bounds__(256) void gemm2_kernel(
    const float* __restrict__ x,             // [2048][256]
    const float* __restrict__ h,             // [2048][8]
    const unsigned short* __restrict__ B2,   // [256][352]
    const unsigned short* __restrict__ G,    // [2048][576]
    float* __restrict__ out)                 // [2048][256]
{
    __shared__ unsigned short As[32 * LDA2S];   // 23040 B
    __shared__ unsigned short Bs[64 * LDB2S];   // 46080 B
    __shared__ float red[32][8];

    const int tid = threadIdx.x, lane = tid & 63, w = tid >> 6;
    const int col = lane & 15, quad = lane >> 4;
    const int b0 = blockIdx.x * 32, n0 = blockIdx.y * 64;

    // stage As x-cols [0,256): fp32 -> bf16
    #pragma unroll
    for (int it = 0; it < 8; ++it) {
        int idx = it * 256 + tid;
        int r = idx >> 6, c = (idx & 63) * 4;
        float4 v = *(const float4*)(x + (size_t)(b0 + r) * CIN + c);
        ushort4 o4;
        o4.x = f2bf(v.x); o4.y = f2bf(v.y); o4.z = f2bf(v.z); o4.w = f2bf(v.w);
        *(ushort4*)&As[r * LDA2S + c] = o4;
    }
    // h cols [320,328)
    {
        int s = tid >> 3, p = tid & 7;
        As[s * LDA2S + 320 + p] = f2bf(h[(size_t)(b0 + s) * NP + p]);
    }
    // sx partials (fp32 from global x)
    {
        int s = tid >> 3, seg = tid & 7;
        const float* xr = x + (size_t)(b0 + s) * CIN + seg * 32;
        float p = 0.f;
        #pragma unroll
        for (int k = 0; k < 8; ++k) {
            float4 v = *(const float4*)(xr + k * 4);
            p += v.x + v.y + v.z + v.w;
        }
        red[s][seg] = p;
    }
    // zero cols [330,352)
    for (int idx = tid; idx < 32 * 22; idx += 256) {
        int s = idx / 22, c = 330 + idx % 22;
        As[s * LDA2S + c] = 0;
    }
    // stage Bs: 64 rows x 352
    #pragma unroll
    for (int it = 0; it < 11; ++it) {
        int idx = it * 256 + tid;
        int r = idx / 44, c = (idx % 44) * 8;
        *(uint4*)&Bs[r * LDB2S + c] =
            *(const uint4*)(B2 + (size_t)(n0 + r) * K2 + c);
    }
    // fold t[s][m] into As cols [256,320)
    {
        int s = tid >> 3, mg = tid & 7;
        const unsigned short* grow = G + (size_t)(b0 + s) * LDG;
        float4 h0 = *(const float4*)(h + (size_t)(b0 + s) * NP);
        float4 h1 = *(const float4*)(h + (size_t)(b0 + s) * NP + 4);
        float hv[8] = {h0.x, h0.y, h0.z, h0.w, h1.x, h1.y, h1.z, h1.w};
        ushort4 cu0 = *(const ushort4*)(grow + 512 + mg * 8);
        ushort4 cu1 = *(const ushort4*)(grow + 512 + mg * 8 + 4);
        float t[8] = {bf2f(cu0.x), bf2f(cu0.y), bf2f(cu0.z), bf2f(cu0.w),
                      bf2f(cu1.x), bf2f(cu1.y), bf2f(cu1.z), bf2f(cu1.w)};
        #pragma unroll
        for (int j = 0; j < 8; ++j) {
            const unsigned short* gp = grow + (mg * 8 + j) * 8;
            ushort4 g0 = *(const ushort4*)gp;
            ushort4 g1 = *(const ushort4*)(gp + 4);
            t[j] += hv[0] * bf2f(g0.x) + hv[1] * bf2f(g0.y)
                  + hv[2] * bf2f(g0.z) + hv[3] * bf2f(g0.w)
                  + hv[4] * bf2f(g1.x) + hv[5] * bf2f(g1.y)
                  + hv[6] * bf2f(g1.z) + hv[7] * bf2f(g1.w);
        }
        ushort4 t0, t1;
        t0.x = f2bf(t[0]); t0.y = f2bf(t[1]); t0.z = f2bf(t[2]); t0.w = f2bf(t[3]);
        t1.x = f2bf(t[4]); t1.y = f2bf(t[5]); t1.z = f2bf(t[6]); t1.w = f2bf(t[7]);
        *(ushort4*)&As[s * LDA2S + 256 + mg * 8]     = t0;
        *(ushort4*)&As[s * LDA2S + 256 + mg * 8 + 4] = t1;
    }
    __syncthreads();
    // sx + ones into As cols 328/329
    if (tid < 32) {
        float s = red[tid][0] + red[tid][1] + red[tid][2] + red[tid][3]
                + red[tid][4] + red[tid][5] + red[tid][6] + red[tid][7];
        As[tid * LDA2S + 328] = f2bf(s);
        As[tid * LDA2S + 329] = 0x3F80;   // 1.0 bf16
    }
    __syncthreads();

    const int mr = (w & 1) * 16, nbw = (w >> 1) * 32;
    floatx4 acc[2] = {floatx4{0,0,0,0}, floatx4{0,0,0,0}};
    #pragma unroll
    for (int ks = 0; ks < 11; ++ks) {
        int kc = ks * 32 + quad * 8;
        short8 af = *(const short8*)&As[(mr + col) * LDA2S + kc];
        #pragma unroll
        for (int f = 0; f < 2; ++f) {
            short8 bfr = *(const short8*)&Bs[(nbw + f * 16 + col) * LDB2S + kc];
            acc[f] = __builtin_amdgcn_mfma_f32_16x16x32_bf16(af, bfr, acc[f], 0, 0, 0);
        }
    }
    #pragma unroll
    for (int f = 0; f < 2; ++f)
        #pragma unroll
        for (int r = 0; r < 4; ++r)
            out[(size_t)(b0 + mr + quad * 4 + r) * COUT + n0 + nbw + f * 16 + col]
                = acc[f][r];
}

extern "C" void kernel_launch(void* const* d_in, const int* in_sizes, int n_in,
                              void* d_out, int out_size, void* d_ws, size_t ws_size,
                              hipStream_t stream) {
    const float* x        = (const float*)d_in[0];
    const float* h        = (const float*)d_in[1];
    const float* index    = (const float*)d_in[2];
    const float* target_w = (const float*)d_in[3];
    const float* target_b = (const float*)d_in[4];
    const float* fcwp_w   = (const float*)d_in[5];
    const float* fcwp_b   = (const float*)d_in[6];
    const float* fcwi_w   = (const float*)d_in[7];
    const float* fcwi_b   = (const float*)d_in[8];
    const float* fcwe_w   = (const float*)d_in[9];
    const float* fcwe_b   = (const float*)d_in[10];
    const float* fcbp_w   = (const float*)d_in[11];
    const float* fcbp_b   = (const float*)d_in[12];
    const float* fcbi_w   = (const float*)d_in[13];
    const float* fcbi_b   = (const float*)d_in[14];
    float* out = (float*)d_out;

    char* ws = (char*)d_ws;
    unsigned short* Bb = (unsigned short*)ws;               // 576*256*2 = 294912
    unsigned short* B2 = (unsigned short*)(ws + 294912);    // 256*352*2 = 180224
    unsigned short* G  = (unsigned short*)(ws + 475136);    // 2048*576*2 = 2359296

    setup_bb<<<36, 256, 0, stream>>>(index, fcwp_w, fcwp_b, fcwi_w, fcwi_b, Bb);

    gemm1_kernel<<<309, 256, 0, stream>>>(
        x, Bb, index, target_w, target_b, fcwe_w, fcwe_b,
        fcbp_w, fcbp_b, fcbi_w, fcbi_b, B2, G);

    gemm2_kernel<<<dim3(B_TOT / 32, COUT / 64), 256, 0, stream>>>(
        x, h, B2, G, out);
}